// Round 12
// baseline (60.594 us; speedup 1.0000x reference)
//
#include <hip/hip_runtime.h>
#include <math.h>

#define TT 8192
#define DD 4096

typedef float  f32x4  __attribute__((ext_vector_type(4)));
typedef short  bf16x8 __attribute__((ext_vector_type(8)));
typedef unsigned int u32;

typedef __attribute__((address_space(3))) void        lds_vp;
typedef const __attribute__((address_space(1))) void  gbl_vp;
// async global->LDS: lane l's 16B lands at lptr + l*16 (wave-uniform lptr, per-lane src)
#define GLD(gp_, lp_) __builtin_amdgcn_global_load_lds((gbl_vp*)(gp_), (lds_vp*)(lp_), 16, 0, 0)

// ---------------- Kernel P: split weights into 3 bf16 planes, frag-ordered ----------------
__global__ __launch_bounds__(128)
void split_w(const float* __restrict__ gw1, const float* __restrict__ nw,
             u32* __restrict__ wfrag) {
  const int s = blockIdx.x;          // 128 k-steps
  const int t = threadIdx.x;
  const int h = t >> 6, l = t & 63;
  const int e = h * 16 + (l & 15);
  const float* src = ((e < 16) ? (gw1 + (size_t)e * DD) : (nw + (size_t)(e - 16) * DD))
                     + s * 32 + ((l >> 4) << 3);
  float f[8];
  *(float4*)&f[0] = *(const float4*)src;
  *(float4*)&f[4] = *(const float4*)(src + 4);
  u32 u0[8], u1[8], u2[8];
#pragma unroll
  for (int i = 0; i < 8; ++i) {
    u0[i] = __float_as_uint(f[i]);
    const float r1 = f[i] - __uint_as_float(u0[i] & 0xFFFF0000u);
    u1[i] = __float_as_uint(r1);
    const float r2 = r1 - __uint_as_float(u1[i] & 0xFFFF0000u);
    u2[i] = __float_as_uint(r2);
  }
  const size_t base = ((size_t)s * 2 + h) * 256 + l * 4;
#define PK(U) make_uint4((U[0]>>16)|(U[1]&0xFFFF0000u), (U[2]>>16)|(U[3]&0xFFFF0000u), \
                         (U[4]>>16)|(U[5]&0xFFFF0000u), (U[6]>>16)|(U[7]&0xFFFF0000u))
  *(uint4*)(wfrag + base)                 = PK(u0);
  *(uint4*)(wfrag + base + 128 * 512)     = PK(u1);   // plane stride = 128*2*256 words
  *(uint4*)(wfrag + base + 2 * 128 * 512) = PK(u2);
#undef PK
}

// ---------------- Kernel M: R6 geometry + T3/T4-correct B pipeline ----------------
// 256 blocks x 16 waves; wave v: slice w=v&7, rowhalf m=v>>3; block = 32 rows.
// B block-shared via GLD into a TRIPLE buffer; per iter: vmcnt(3) retires exactly
// buf[sl] (buf[sl+1] stays in flight ~2 iters), raw s_barrier (no drain), then issue
// B(sl+2) into the buffer all waves just finished reading. Never vmcnt(0) mid-loop.
// red[] overlays buf[1] post-loop; sg2 via wave-0 GLD (keeps vmcnt counts exact).
// Numerics identical to R6 (passed): same consume layout, split, MFMA order, reduce.
__global__ __launch_bounds__(1024)
void gate_mega(const float* __restrict__ x, const u32* __restrict__ wfrag,
               const float* __restrict__ noise, const float* __restrict__ gw2,
               float* __restrict__ out, float* __restrict__ part2) {
  __shared__ __align__(16) u32 bufB[3][8][6][256];   // 3 x 48 KB
  __shared__ float sg2[256];
  float* red = (float*)&bufB[1][0][0][0];            // 32 KB overlay (safe post-loop)

  const int t = threadIdx.x;
  const int v = t >> 6, l = t & 63;
  const int w = v & 7;                 // k-slice
  const int m = v >> 3;                // row half
  const int rt = blockIdx.x;           // 32-row tile

  const int r = l & 15, c = l >> 4;
  const float* xp = x + (size_t)(rt * 32 + m * 16 + r) * DD + w * 512 + (c << 3);

  // wave v stages chunks q=3v..3v+2: slice s=q/6, part p=q%6 (plane p>>1, half p&1)
  const u32* srcb[3];
  int dsto[3];
#pragma unroll
  for (int i = 0; i < 3; ++i) {
    const int q = 3 * v + i, s = q / 6, p = q % 6;
    srcb[i] = wfrag + (size_t)(p >> 1) * 65536 + (p & 1) * 256
                    + (size_t)s * 16 * 512 + (l << 2);
    dsto[i] = (s * 6 + p) * 256;
  }
  u32* const b0 = &bufB[0][0][0][0];
  u32* const b1 = &bufB[1][0][0][0];
  u32* const b2 = &bufB[2][0][0][0];

  // sg2 via wave-0 GLD (one instruction; oldest in wave 0's vmcnt FIFO)
  if (v == 0) GLD(gw2 + (l << 2), &sg2[0]);
  // prologue: B(0)->buf0, B(1)->buf1
#pragma unroll
  for (int i = 0; i < 3; ++i) GLD(srcb[i], b0 + dsto[i]);
#pragma unroll
  for (int i = 0; i < 3; ++i) GLD(srcb[i] + 512, b1 + dsto[i]);

  f32x4 ag0 = {0,0,0,0}, ag1 = ag0, ag2 = ag0, an0 = ag0, an1 = ag0, an2 = ag0;

  for (int sl = 0; sl < 16; ++sl) {
    // retire exactly buf[sl]'s chunks; keep buf[sl+1]'s in flight
    if (sl < 15) asm volatile("s_waitcnt vmcnt(3)" ::: "memory");
    else         asm volatile("s_waitcnt vmcnt(0)" ::: "memory");
    __builtin_amdgcn_s_barrier();      // raw barrier: no compiler drain

    // issue B(sl+2) into buf[(sl+2)%3] -- all waves are past reading it
    if (sl + 2 < 16) {
      u32* const bn = (((sl + 2) % 3) == 0) ? b0 : ((((sl + 2) % 3) == 1) ? b1 : b2);
#pragma unroll
      for (int i = 0; i < 3; ++i) GLD(srcb[i] + (size_t)(sl + 2) * 512, bn + dsto[i]);
    }

    // consume buf[sl%3]
    const u32* wb = &bufB[sl % 3][w][0][0] + (l << 2);
    const bf16x8 bg0 = *(const bf16x8*)(wb);
    const bf16x8 bn0 = *(const bf16x8*)(wb + 256);
    const bf16x8 bg1 = *(const bf16x8*)(wb + 512);
    const bf16x8 bn1 = *(const bf16x8*)(wb + 768);
    const bf16x8 bg2 = *(const bf16x8*)(wb + 1024);
    const bf16x8 bn2 = *(const bf16x8*)(wb + 1280);

    float f[8];
    *(float4*)&f[0] = *(const float4*)(xp + sl * 32);
    *(float4*)&f[4] = *(const float4*)(xp + sl * 32 + 4);

    u32 pk[12] __attribute__((aligned(16)));
#pragma unroll
    for (int p = 0; p < 4; ++p) {
      const float fa = f[2 * p], fb = f[2 * p + 1];
      const u32  a  = __float_as_uint(fa);
      const float ra1 = fa - __uint_as_float(a & 0xFFFF0000u);
      const u32  a1 = __float_as_uint(ra1);
      const float ra2 = ra1 - __uint_as_float(a1 & 0xFFFF0000u);
      const u32  a2 = __float_as_uint(ra2);
      const u32  b  = __float_as_uint(fb);
      const float rb1 = fb - __uint_as_float(b & 0xFFFF0000u);
      const u32  b1 = __float_as_uint(rb1);
      const float rb2 = rb1 - __uint_as_float(b1 & 0xFFFF0000u);
      const u32  b2 = __float_as_uint(rb2);
      pk[p]     = (a  >> 16) | (b  & 0xFFFF0000u);
      pk[4 + p] = (a1 >> 16) | (b1 & 0xFFFF0000u);
      pk[8 + p] = (a2 >> 16) | (b2 & 0xFFFF0000u);
    }
    const bf16x8 a0 = *(const bf16x8*)&pk[0];
    const bf16x8 a1 = *(const bf16x8*)&pk[4];
    const bf16x8 a2 = *(const bf16x8*)&pk[8];

    ag0 = __builtin_amdgcn_mfma_f32_16x16x32_bf16(a0, bg0, ag0, 0, 0, 0);
    an0 = __builtin_amdgcn_mfma_f32_16x16x32_bf16(a0, bn0, an0, 0, 0, 0);
    ag1 = __builtin_amdgcn_mfma_f32_16x16x32_bf16(a0, bg1, ag1, 0, 0, 0);
    an1 = __builtin_amdgcn_mfma_f32_16x16x32_bf16(a0, bn1, an1, 0, 0, 0);
    ag2 = __builtin_amdgcn_mfma_f32_16x16x32_bf16(a1, bg0, ag2, 0, 0, 0);
    an2 = __builtin_amdgcn_mfma_f32_16x16x32_bf16(a1, bn0, an2, 0, 0, 0);
    ag0 = __builtin_amdgcn_mfma_f32_16x16x32_bf16(a0, bg2, ag0, 0, 0, 0);
    an0 = __builtin_amdgcn_mfma_f32_16x16x32_bf16(a0, bn2, an0, 0, 0, 0);
    ag1 = __builtin_amdgcn_mfma_f32_16x16x32_bf16(a1, bg1, ag1, 0, 0, 0);
    an1 = __builtin_amdgcn_mfma_f32_16x16x32_bf16(a1, bn1, an1, 0, 0, 0);
    ag2 = __builtin_amdgcn_mfma_f32_16x16x32_bf16(a2, bg0, ag2, 0, 0, 0);
    an2 = __builtin_amdgcn_mfma_f32_16x16x32_bf16(a2, bn0, an2, 0, 0, 0);
  }

  __syncthreads();   // full drain; buffers dead, red overlay becomes valid

  const f32x4 cg = ag0 + ag1 + ag2;
  const f32x4 cn = an0 + an1 + an2;
  // C/D: col(lane&15)=expert, row=(lane>>4)*4+reg [m89]. red[slice][m*512 + e*16 + row].
#pragma unroll
  for (int j = 0; j < 4; ++j) {
    red[w * 1024 + m * 512 + r * 16 + (c * 4 + j)]        = cg[j];
    red[w * 1024 + m * 512 + (16 + r) * 16 + (c * 4 + j)] = cn[j];
  }
  __syncthreads();
  // 1024-thread reduce across the 8 k-slices, ascending order (bitwise-stable).
  {
    float s = red[t];
#pragma unroll
    for (int ww = 1; ww < 8; ++ww) s += red[ww * 1024 + t];
    red[t] = s;
  }
  __syncthreads();

  if (t < 32) {
    const int mg = t >> 4, rr = t & 15;
    const int row = rt * 32 + t;
    float dot[32];
#pragma unroll
    for (int e = 0; e < 32; ++e) dot[e] = red[mg * 512 + e * 16 + rr];
    float h[16];
#pragma unroll
    for (int e = 0; e < 16; ++e) h[e] = tanhf(dot[e]);
    float lg[16], nc[16], ln[16], lo[16];
#pragma unroll
    for (int j = 0; j < 16; ++j) {
      float s = 0.f;
#pragma unroll
      for (int e = 0; e < 16; ++e) s = fmaf(h[e], sg2[j * 16 + e], s);
      lg[j] = s;
      const float vv = dot[16 + j];
      nc[j] = fmaxf(vv, 0.f) + log1pf(expf(-fabsf(vv))) + 0.01f;
      ln[j] = noise[(size_t)row * 16 + j] * nc[j];
      lo[j] = lg[j] + ln[j];
    }
    int i0 = 0; float m0 = lo[0];
#pragma unroll
    for (int j = 1; j < 16; ++j) if (lo[j] > m0) { m0 = lo[j]; i0 = j; }
    int i1 = -1; float m1 = -1e30f;
#pragma unroll
    for (int j = 0; j < 16; ++j) if (j != i0 && lo[j] > m1) { m1 = lo[j]; i1 = j; }
    float m2 = -1e30f;
#pragma unroll
    for (int j = 0; j < 16; ++j) if (j != i0 && j != i1 && lo[j] > m2) m2 = lo[j];

    const float e1 = expf(m1 - m0);
    const float s0 = 1.f / (1.f + e1);
    const float s1 = e1 / (1.f + e1);
    out[(size_t)row * 2]             = (float)i0;
    out[(size_t)row * 2 + 1]         = (float)i1;
    out[16384 + (size_t)row * 2]     = s0;
    out[16384 + (size_t)row * 2 + 1] = s1;

    float cacc[32];
#pragma unroll
    for (int j = 0; j < 16; ++j) {
      cacc[j] = (j == i0) ? s0 : ((j == i1) ? s1 : 0.f);
      const bool in = ln[j] > m2;
      const float thr = in ? m2 : m1;
      const float z = (lg[j] - thr) / nc[j];
      cacc[16 + j] = 0.5f * (1.f + erff(z * 0.70710678118654752f));
    }
#pragma unroll
    for (int off = 1; off < 16; off <<= 1) {
#pragma unroll
      for (int k = 0; k < 32; ++k) cacc[k] += __shfl_xor(cacc[k], off, 16);
    }
    const int g = rt * 2 + mg;
    float v0 = 0.f, v1 = 0.f;
#pragma unroll
    for (int k = 0; k < 16; ++k) if (rr == k) { v0 = cacc[k]; v1 = cacc[16 + k]; }
    part2[(size_t)g * 32 + rr]      = v0;
    part2[(size_t)g * 32 + 16 + rr] = v1;
  }
}

// ---------------- Kernel C: reduce per-block partials -> cv^2 loss ----------------
__global__ __launch_bounds__(256)
void gate_loss_k(const float* __restrict__ part2, float* __restrict__ out) {
  __shared__ float sred[8][32];
  const int t = threadIdx.x;        // 256
  const int k = t & 31, s = t >> 5; // expert, group-slice (8 slices of 64 groups)
  float acc = 0.f;
#pragma unroll 8
  for (int i = 0; i < 64; ++i) acc += part2[(size_t)(s * 64 + i) * 32 + k];
  sred[s][k] = acc;
  __syncthreads();
  if (t == 0) {
    float res = 0.f;
    for (int g = 0; g < 2; ++g) {
      float vals[16];
      float mu = 0.f;
      for (int j = 0; j < 16; ++j) {
        float s2 = 0.f;
        for (int ss = 0; ss < 8; ++ss) s2 += sred[ss][g * 16 + j];
        vals[j] = s2;
        mu += s2;
      }
      mu *= (1.f / 16.f);
      float var = 0.f;
      for (int j = 0; j < 16; ++j) { const float d = vals[j] - mu; var += d * d; }
      var *= (1.f / 15.f);
      res += var / (mu * mu + 1e-10f);
    }
    out[32768] = res * 0.01f;
  }
}

extern "C" void kernel_launch(void* const* d_in, const int* in_sizes, int n_in,
                              void* d_out, int out_size, void* d_ws, size_t ws_size,
                              hipStream_t stream) {
  const float* x     = (const float*)d_in[0];
  const float* gw1   = (const float*)d_in[1];
  const float* gw2   = (const float*)d_in[2];
  const float* nw    = (const float*)d_in[3];
  const float* noise = (const float*)d_in[4];
  float* out   = (float*)d_out;
  u32*   wfrag = (u32*)d_ws;                                   // 768 KB, fully written
  float* part2 = (float*)((char*)d_ws + (size_t)768 * 1024);   // 64 KB, fully written
  split_w<<<128, 128, 0, stream>>>(gw1, nw, wfrag);
  gate_mega<<<256, 1024, 0, stream>>>(x, wfrag, noise, gw2, out, part2);
  gate_loss_k<<<1, 256, 0, stream>>>(part2, out);
}